// Round 7
// baseline (64.546 us; speedup 1.0000x reference)
//
#include <hip/hip_runtime.h>

// out[b,po] = sum_k W[po,k]*x[b,k] + bias[po];  B=32, NPO=4096, K=16384.
// 3 kernels: (1) precast x->bf16 (1 MB in d_ws); (2) main: 256 blocks =
// 64 po-groups x 4 k-quarters, kh = blockIdx&3 -> constant per XCD (8%4==0),
// so each XCD's 32 blocks share one 0.25 MB x quarter-slice (L2-resident,
// x HBM ~0). POT=64, K-quarter 4096 in 16 chunks of 256; distance-2 reg
// prefetch -> bf16 LDS dbuf; raw s_barrier + lgkmcnt(0) (no vmcnt drain).
// 8 waves = 4 potiles x 2 btiles, each owns a 16x16 tile: 8 mfma/chunk,
// no epilogue reduction; fp32 partials to d_ws. (3) combine: +4 quarters +bias.

typedef __attribute__((ext_vector_type(8))) __bf16 bf16x8;
typedef __attribute__((ext_vector_type(4))) __bf16 bf16x4;
typedef __attribute__((ext_vector_type(4))) float f32x4;

#define KDIM 16384
#define NPO  4096
#define POT  64
#define CHK  256
#define KQTR 4096    // k per quarter
#define NCHH 16      // chunks per quarter
#define WSTR 264     // padded LDS k-stride (bf16): 528 B

__device__ inline bf16x8 cvt8(float4 a, float4 b) {
  bf16x8 r;
  r[0] = (__bf16)a.x; r[1] = (__bf16)a.y; r[2] = (__bf16)a.z; r[3] = (__bf16)a.w;
  r[4] = (__bf16)b.x; r[5] = (__bf16)b.y; r[6] = (__bf16)b.z; r[7] = (__bf16)b.w;
  return r;
}

__global__ __launch_bounds__(256)
void precast_x(const float* __restrict__ x, __bf16* __restrict__ xbf) {
  const int i = blockIdx.x * 256 + threadIdx.x;   // 131072 float4s
  float4 v = reinterpret_cast<const float4*>(x)[i];
  bf16x4 o;
  o[0] = (__bf16)v.x; o[1] = (__bf16)v.y; o[2] = (__bf16)v.z; o[3] = (__bf16)v.w;
  reinterpret_cast<bf16x4*>(xbf)[i] = o;
}

__global__ __launch_bounds__(512, 2)
void trace_main(const __bf16* __restrict__ xbf, const float* __restrict__ w,
                float* __restrict__ part) {
  __shared__ __bf16 wbuf[2][64 * WSTR];   // 66 KB
  __shared__ __bf16 xbuf[2][32 * WSTR];   // 33 KB

  const int t    = threadIdx.x;
  const int lane = t & 63;
  const int wv   = t >> 6;        // 0..7
  const int btile  = wv & 1;      // 16 batches
  const int potile = wv >> 1;     // 0..3 (16 po each)
  const int kh    = blockIdx.x & 3;    // constant per XCD (blockIdx%8 rr, 8%4==0)
  const int group = blockIdx.x >> 2;   // po group (64 rows)
  const int po_base = group * POT;

  // staging coords: w 64r x 256c fp32 (128 B/thread), x 32r x 256c bf16 (32 B/thread)
  const int wrow_s = t >> 3, wcol_s = (t & 7) * 32;
  const int xrow_s = t >> 4, xcol_s = (t & 15) * 16;
  const float*  wg = w   + (size_t)(po_base + wrow_s) * KDIM + (size_t)kh * KQTR + wcol_s;
  const __bf16* xg = xbf + (size_t)xrow_s * KDIM + (size_t)kh * KQTR + xcol_s;
  const int woff = wrow_s * WSTR + wcol_s;
  const int xoff = xrow_s * WSTR + xcol_s;

  // fragment coords (A = x rows, B = w rows; same lane->k rule on both)
  const int lrow = lane & 15, lhi = lane >> 4;
  const int wfo = (potile * 16 + lrow) * WSTR + lhi * 8;
  const int xfo = (btile * 16 + lrow) * WSTR + lhi * 8;

  f32x4 acc = {0.f, 0.f, 0.f, 0.f};

#define ISSUE(W8, X2, c) do {                              \
    const float*  wp_ = wg + (size_t)(c) * CHK;            \
    const __bf16* xp_ = xg + (size_t)(c) * CHK;            \
    _Pragma("unroll")                                      \
    for (int j_ = 0; j_ < 8; ++j_)                         \
      W8[j_] = *(const float4*)(wp_ + j_ * 4);             \
    X2[0] = *(const bf16x8*)(xp_);                         \
    X2[1] = *(const bf16x8*)(xp_ + 8);                     \
  } while (0)

#define WRITE_LDS(W8, X2, h) do {                          \
    *(bf16x8*)&wbuf[h][woff]      = cvt8(W8[0], W8[1]);    \
    *(bf16x8*)&wbuf[h][woff + 8]  = cvt8(W8[2], W8[3]);    \
    *(bf16x8*)&wbuf[h][woff + 16] = cvt8(W8[4], W8[5]);    \
    *(bf16x8*)&wbuf[h][woff + 24] = cvt8(W8[6], W8[7]);    \
    *(bf16x8*)&xbuf[h][xoff]      = X2[0];                 \
    *(bf16x8*)&xbuf[h][xoff + 8]  = X2[1];                 \
  } while (0)

#define COMPUTE(h) do {                                    \
    _Pragma("unroll")                                      \
    for (int j_ = 0; j_ < 8; ++j_) {                       \
      bf16x8 bf_ = *(const bf16x8*)&wbuf[h][wfo + j_ * 32];\
      bf16x8 af_ = *(const bf16x8*)&xbuf[h][xfo + j_ * 32];\
      acc = __builtin_amdgcn_mfma_f32_16x16x32_bf16(af_, bf_, acc, 0, 0, 0); \
    }                                                      \
  } while (0)

  // lgkmcnt(0): our ds ops done; NO vmcnt drain -> prefetch survives barrier
#define BARRIER() do {                                     \
    asm volatile("s_waitcnt lgkmcnt(0)" ::: "memory");     \
    __builtin_amdgcn_s_barrier();                          \
  } while (0)

  float4 raw[8], rbw[8];
  bf16x8 rax[2], rbx[2];

  // prologue: chunk0 -> LDS[0]; chunk1 in flight
  ISSUE(raw, rax, 0);
  WRITE_LDS(raw, rax, 0);
  ISSUE(raw, rax, 1);
  BARRIER();

  for (int c = 0; c < NCHH; c += 2) {
    if (c + 2 < NCHH) ISSUE(rbw, rbx, c + 2);
    COMPUTE(0);
    WRITE_LDS(raw, rax, 1);                     // chunk c+1 (vmcnt counted)
    BARRIER();
    if (c + 3 < NCHH) ISSUE(raw, rax, c + 3);
    COMPUTE(1);
    if (c + 2 < NCHH) WRITE_LDS(rbw, rbx, 0);   // chunk c+2
    BARRIER();
  }

#undef ISSUE
#undef WRITE_LDS
#undef COMPUTE
#undef BARRIER

  // direct partial write: D layout (m89/m91): col = lane&15 (po), row = (lane>>4)*4+reg (b)
  const int b  = btile * 16 + lhi * 4;
  const int pl = potile * 16 + lrow;
#pragma unroll
  for (int r = 0; r < 4; ++r)
    part[(((size_t)kh * 64 + group) * 32 + (b + r)) * 64 + pl] = acc[r];
}

__global__ __launch_bounds__(256)
void combine(const float* __restrict__ part, const float* __restrict__ bias,
             float* __restrict__ out) {
  const int i = blockIdx.x * 256 + threadIdx.x;   // 0..131071 = (g*32+b)*64+pl
  const int pl = i & 63, b = (i >> 6) & 31, g = i >> 11;
  const float v = part[i] + part[131072 + i] + part[262144 + i] + part[393216 + i]
                + bias[g * 64 + pl];
  out[(size_t)b * NPO + g * 64 + pl] = v;
}

extern "C" void kernel_launch(void* const* d_in, const int* in_sizes, int n_in,
                              void* d_out, int out_size, void* d_ws, size_t ws_size,
                              hipStream_t stream) {
  const float* x    = (const float*)d_in[0];
  const float* wgt  = (const float*)d_in[1];
  const float* bias = (const float*)d_in[2];
  float* out = (float*)d_out;

  __bf16* xbf  = (__bf16*)d_ws;                        // 1 MB
  float*  part = (float*)((char*)d_ws + (1 << 20));    // 2 MB (4 k-quarters)

  hipLaunchKernelGGL(precast_x, dim3(512), dim3(256), 0, stream, x, xbf);
  hipLaunchKernelGGL(trace_main, dim3(256), dim3(512), 0, stream, xbf, wgt, part);
  hipLaunchKernelGGL(combine, dim3(512), dim3(256), 0, stream, part, bias, out);
}

// Round 8
// 62.486 us; speedup vs baseline: 1.0330x; 1.0330x over previous
//
#include <hip/hip_runtime.h>

// out[b,po] = sum_k W[po,k]*x[b,k] + bias[po];  B=32, NPO=4096, K=16384.
// 3 kernels: (1) precast x->bf16 (1 MB); (2) main: 512 blocks = 128 po-groups
// x 4 k-quarters -> 2 blocks/CU (the overlap resource: one block's MFMA hides
// the other's staging vmcnt/barrier). kh = blockIdx&3 is constant per XCD
// (blockIdx%8 rr, 8%4==0) -> all blocks of an XCD share one 0.25 MB x slice
// (L2-resident). POT=32, 16 chunks of 256 k; distance-2 reg prefetch -> bf16
// LDS dbuf; raw s_barrier + lgkmcnt(0) only (no vmcnt drain). 8 waves =
// 2 btile x 2 potile x 2 kq, 4 mfma 16x16x32/chunk; LDS kq-reduce; fp32
// partials. (3) combine: sum 4 quarters + bias.

typedef __attribute__((ext_vector_type(8))) __bf16 bf16x8;
typedef __attribute__((ext_vector_type(4))) __bf16 bf16x4;
typedef __attribute__((ext_vector_type(4))) float f32x4;

#define KDIM 16384
#define NPO  4096
#define POT  32
#define CHK  256
#define KQTR 4096    // k per quarter
#define NCHH 16      // chunks per quarter
#define WSTR 264     // padded LDS k-stride (bf16): 528 B

__device__ inline bf16x8 cvt8(float4 a, float4 b) {
  bf16x8 r;
  r[0] = (__bf16)a.x; r[1] = (__bf16)a.y; r[2] = (__bf16)a.z; r[3] = (__bf16)a.w;
  r[4] = (__bf16)b.x; r[5] = (__bf16)b.y; r[6] = (__bf16)b.z; r[7] = (__bf16)b.w;
  return r;
}

__global__ __launch_bounds__(256)
void precast_x(const float* __restrict__ x, __bf16* __restrict__ xbf) {
  const int i = blockIdx.x * 256 + threadIdx.x;   // 131072 float4s
  float4 v = reinterpret_cast<const float4*>(x)[i];
  bf16x4 o;
  o[0] = (__bf16)v.x; o[1] = (__bf16)v.y; o[2] = (__bf16)v.z; o[3] = (__bf16)v.w;
  reinterpret_cast<bf16x4*>(xbf)[i] = o;
}

__global__ __launch_bounds__(512, 4)
void trace_main(const __bf16* __restrict__ xbf, const float* __restrict__ w,
                float* __restrict__ part) {
  __shared__ __bf16 wbuf[2][32 * WSTR];   // 33.8 KB
  __shared__ __bf16 xbuf[2][32 * WSTR];   // 33.8 KB
  __shared__ float  red[2048];            // 8 KB   -> 75.6 KB total (2 blocks/CU)

  const int t    = threadIdx.x;
  const int lane = t & 63;
  const int wv   = t >> 6;        // 0..7
  const int btile  = wv & 1;      // 16 batches
  const int potile = (wv >> 1) & 1;
  const int kq     = wv >> 2;     // 128-k half of chunk
  const int kh    = blockIdx.x & 3;    // constant per XCD
  const int group = blockIdx.x >> 2;   // po group (32 rows)
  const int po_base = group * POT;

  // staging coords: both tiles 32 rows x 256 cols; 16 elems/thread
  const int row_s = t >> 4;
  const int col_s = (t & 15) * 16;
  const float*  wg = w   + (size_t)(po_base + row_s) * KDIM + (size_t)kh * KQTR + col_s;
  const __bf16* xg = xbf + (size_t)row_s * KDIM + (size_t)kh * KQTR + col_s;
  const int soff = row_s * WSTR + col_s;

  // fragment coords (A = x, B = w; same lane->k rule on both operands)
  const int lrow = lane & 15, lhi = lane >> 4;
  const int fk  = kq * 128 + lhi * 8;
  const int wfo = (potile * 16 + lrow) * WSTR + fk;
  const int xfo = (btile * 16 + lrow) * WSTR + fk;

  f32x4 acc = {0.f, 0.f, 0.f, 0.f};

#define ISSUE(W4, X2, c) do {                              \
    const float*  wp_ = wg + (size_t)(c) * CHK;            \
    const __bf16* xp_ = xg + (size_t)(c) * CHK;            \
    W4[0] = *(const float4*)(wp_);                         \
    W4[1] = *(const float4*)(wp_ + 4);                     \
    W4[2] = *(const float4*)(wp_ + 8);                     \
    W4[3] = *(const float4*)(wp_ + 12);                    \
    X2[0] = *(const bf16x8*)(xp_);                         \
    X2[1] = *(const bf16x8*)(xp_ + 8);                     \
  } while (0)

#define WRITE_LDS(W4, X2, h) do {                          \
    *(bf16x8*)&wbuf[h][soff]     = cvt8(W4[0], W4[1]);     \
    *(bf16x8*)&wbuf[h][soff + 8] = cvt8(W4[2], W4[3]);     \
    *(bf16x8*)&xbuf[h][soff]     = X2[0];                  \
    *(bf16x8*)&xbuf[h][soff + 8] = X2[1];                  \
  } while (0)

#define COMPUTE(h) do {                                    \
    _Pragma("unroll")                                      \
    for (int j_ = 0; j_ < 4; ++j_) {                       \
      bf16x8 bf_ = *(const bf16x8*)&wbuf[h][wfo + j_ * 32];\
      bf16x8 af_ = *(const bf16x8*)&xbuf[h][xfo + j_ * 32];\
      acc = __builtin_amdgcn_mfma_f32_16x16x32_bf16(af_, bf_, acc, 0, 0, 0); \
    }                                                      \
  } while (0)

  // lgkmcnt(0): our ds ops done; NO vmcnt drain -> prefetch survives barrier
#define BARRIER() do {                                     \
    asm volatile("s_waitcnt lgkmcnt(0)" ::: "memory");     \
    __builtin_amdgcn_s_barrier();                          \
  } while (0)

  float4 raw[4], rbw[4];
  bf16x8 rax[2], rbx[2];

  // prologue: chunk0 -> LDS[0]; chunk1 in flight
  ISSUE(raw, rax, 0);
  WRITE_LDS(raw, rax, 0);
  ISSUE(raw, rax, 1);
  BARRIER();

  for (int c = 0; c < NCHH; c += 2) {
    if (c + 2 < NCHH) ISSUE(rbw, rbx, c + 2);
    COMPUTE(0);
    WRITE_LDS(raw, rax, 1);                     // chunk c+1 (vmcnt counted)
    BARRIER();
    if (c + 3 < NCHH) ISSUE(raw, rax, c + 3);
    COMPUTE(1);
    if (c + 2 < NCHH) WRITE_LDS(rbw, rbx, 0);   // chunk c+2
    BARRIER();
  }

#undef ISSUE
#undef WRITE_LDS
#undef COMPUTE
#undef BARRIER

  // epilogue: reduce the 2 kq partials per (btile,potile) tile
  red[wv * 256 + lane * 4 + 0] = acc[0];
  red[wv * 256 + lane * 4 + 1] = acc[1];
  red[wv * 256 + lane * 4 + 2] = acc[2];
  red[wv * 256 + lane * 4 + 3] = acc[3];
  __syncthreads();

#pragma unroll
  for (int i0 = 0; i0 < 2; ++i0) {
    const int i    = i0 * 512 + t;     // 0..1023
    const int tile = i >> 8;           // potile*2 + btile
    const int slot = i & 255;
    const float v = red[tile * 256 + slot] + red[(tile + 4) * 256 + slot];
    const int ln = slot >> 2, rg = slot & 3;
    // D layout (m89/m91): col = lane&15 (po), row = (lane>>4)*4 + reg (b)
    const int b  = (tile & 1) * 16 + (ln >> 4) * 4 + rg;
    const int pl = (tile >> 1) * 16 + (ln & 15);
    part[((size_t)(kh * 128 + group) * 32 + b) * 32 + pl] = v;
  }
}

__global__ __launch_bounds__(256)
void combine(const float* __restrict__ part, const float* __restrict__ bias,
             float* __restrict__ out) {
  const int i = blockIdx.x * 256 + threadIdx.x;   // 0..131071 = (g*32+b)*32+pl
  const int pl = i & 31, b = (i >> 5) & 31, g = i >> 10;
  const float v = part[i] + part[131072 + i] + part[262144 + i] + part[393216 + i]
                + bias[g * 32 + pl];
  out[(size_t)b * NPO + g * 32 + pl] = v;
}

extern "C" void kernel_launch(void* const* d_in, const int* in_sizes, int n_in,
                              void* d_out, int out_size, void* d_ws, size_t ws_size,
                              hipStream_t stream) {
  const float* x    = (const float*)d_in[0];
  const float* wgt  = (const float*)d_in[1];
  const float* bias = (const float*)d_in[2];
  float* out = (float*)d_out;

  __bf16* xbf  = (__bf16*)d_ws;                        // 1 MB
  float*  part = (float*)((char*)d_ws + (1 << 20));    // 2 MB (4 k-quarters)

  hipLaunchKernelGGL(precast_x, dim3(512), dim3(256), 0, stream, x, xbf);
  hipLaunchKernelGGL(trace_main, dim3(512), dim3(512), 0, stream, xbf, wgt, part);
  hipLaunchKernelGGL(combine, dim3(512), dim3(256), 0, stream, part, bias, out);
}